// Round 20
// baseline (232.098 us; speedup 1.0000x reference)
//
#include <hip/hip_runtime.h>
#include <hip/hip_bf16.h>

#define PI_F 3.14159265358979323846f

typedef short  bf16x8 __attribute__((ext_vector_type(8)));
typedef unsigned short u16x8 __attribute__((ext_vector_type(8)));
typedef float  f32x4  __attribute__((ext_vector_type(4)));

// ---- ws layout (bytes) ----
#define OUT3_OFF  0                       // [3][1024][257] f32 = 3,158,016 B
#define TPACK_OFF 3158016                 // [64 tiles][64][8] bf16 = 65,536 B
#define WPACK_OFF (3158016 + 65536)       // 1344 tile-pairs x 2 KB = 2,752,512 B

static __device__ __forceinline__ unsigned short f2bf(float x) {
    unsigned int u = __float_as_uint(x);
    unsigned int r = (u + 0x7fffu + ((u >> 16) & 1u)) >> 16;   // RNE
    return (unsigned short)r;
}

// pack two f32 -> one u32 of 2 bf16 (lo = a, hi = b) in ONE instruction
static __device__ __forceinline__ unsigned int pk_bf16(float a, float b) {
    unsigned int r;
    asm("v_cvt_pk_bf16_f32 %0, %1, %2" : "=v"(r) : "v"(a), "v"(b));
    return r;
}

static __device__ __forceinline__ float sigm(float x) {
    return 1.f / (1.f + expf(-x));
}

static __device__ __forceinline__ float bf_lo(unsigned int u) {
    return __uint_as_float(u << 16);
}
static __device__ __forceinline__ float bf_hi(unsigned int u) {
    return __uint_as_float(u & 0xffff0000u);
}

// ------------------------------------------------------------------
// wpack: pre-split all MLP weights into bf16 hi/lo B-fragment tiles.
// (unchanged from round 19)
// ------------------------------------------------------------------
__global__ __launch_bounds__(256) void wpack(
    const float* __restrict__ Win, const float* __restrict__ Wh,
    const float* __restrict__ Wout, unsigned short* __restrict__ wp)
{
    int g = blockIdx.x * 256 + threadIdx.x;     // 1344*64 = 86016 exactly
    int t = g >> 6, l = g & 63;
    int s = t / 448, lt = t % 448;
    int layer, base;
    if (lt < 64)       { layer = 0; base = 0;   }
    else if (lt < 192) { layer = 1; base = 64;  }
    else if (lt < 320) { layer = 2; base = 192; }
    else               { layer = 3; base = 320; }
    int local = lt - base, ks = local >> 4, nt = local & 15;

    u16x8 hv, lv;
    #pragma unroll
    for (int j = 0; j < 8; ++j) {
        int k = ks*32 + ((l >> 4) << 3) + j;
        int n = nt*16 + (l & 15);
        float w;
        if (layer == 0)      w = Win[(size_t)s*32768 + k*256 + n];
        else if (layer == 1) w = Wh[((size_t)s*2 + 0)*65536 + k*256 + n];
        else if (layer == 2) w = Wh[((size_t)s*2 + 1)*65536 + k*256 + n];
        else                 w = Wout[(size_t)s*65792 + k*257 + n];
        unsigned int ph = pk_bf16(w, 0.f);
        float fh = bf_lo(ph);
        hv[j] = (unsigned short)(ph & 0xffffu);
        lv[j] = (unsigned short)(pk_bf16(w - fh, 0.f) & 0xffffu);
    }
    *(u16x8*)(wp + (size_t)(t*2    )*512 + l*8) = hv;
    *(u16x8*)(wp + (size_t)(t*2 + 1)*512 + l*8) = lv;
}

// ------------------------------------------------------------------
// mlp_mfma: three LinearOutputStacks via split-bf16 MFMA.
// ROUND 20: 16 rows/block, grid (64, 3) = 192 blocks (4x CU coverage).
// ------------------------------------------------------------------
__global__ __launch_bounds__(512) void mlp_mfma(
    const float* __restrict__ latents,
    const float* __restrict__ b_in, const float* __restrict__ b_h,
    const float* __restrict__ b_out, const float* __restrict__ Wout,
    const unsigned short* __restrict__ wp,
    float* __restrict__ out3)
{
    __shared__ float xs[16*260];                 // 16,640 B fp32 staging
    __shared__ unsigned int xh[16*132];          // 8,448 B bf16-hi pairs
    __shared__ unsigned int xl[16*132];          // 8,448 B bf16-lo pairs
    __shared__ float mrow[16], rrow[16];

    const int tid  = threadIdx.x;
    const int s    = blockIdx.y;
    const int row0 = blockIdx.x * 16;
    const int l  = tid & 63;
    const int wv = tid >> 6;                     // 0..7: 32-col slice
    const int m0 = l & 15;
    const int ac = l >> 4;

    const int4* Wp4 = (const int4*)wp;
    const int4* xh4 = (const int4*)xh;           // row stride 33 int4
    const int4* xl4 = (const int4*)xl;

    // ---- load + split latents (K=128): 1024 k-pairs ----
    #pragma unroll
    for (int i = 0; i < 2; ++i) {
        int idx = tid + i*512;
        int r = idx >> 6, kp = idx & 63;
        const float* lp = latents + (size_t)(row0 + r)*128 + 2*kp;
        float x0 = lp[0], x1 = lp[1];
        unsigned int u = pk_bf16(x0, x1);
        xh[r*132 + kp] = u;
        xl[r*132 + kp] = pk_bf16(x0 - bf_lo(u), x1 - bf_hi(u));
    }
    __syncthreads();

    for (int L = 0; L < 4; ++L) {
        const int kt    = (L == 0) ? 4 : 8;
        const int tbase = s*448 + ((L == 0) ? 0 : (L == 1) ? 64 : (L == 2) ? 192 : 320);

        f32x4 acc[2];
        acc[0] = (f32x4){0.f, 0.f, 0.f, 0.f};
        acc[1] = (f32x4){0.f, 0.f, 0.f, 0.f};

        for (int ks = 0; ks < kt; ++ks) {
            const int t0 = tbase + ks*16 + wv*2;
            int4 bh0 = Wp4[(size_t)(t0*2    )*64 + l];
            int4 bl0 = Wp4[(size_t)(t0*2 + 1)*64 + l];
            int4 bh1 = Wp4[(size_t)(t0*2 + 2)*64 + l];
            int4 bl1 = Wp4[(size_t)(t0*2 + 3)*64 + l];
            bf16x8 BH0 = *(bf16x8*)&bh0, BL0 = *(bf16x8*)&bl0;
            bf16x8 BH1 = *(bf16x8*)&bh1, BL1 = *(bf16x8*)&bl1;
            int4 ah = xh4[m0*33 + ks*4 + ac];
            int4 al = xl4[m0*33 + ks*4 + ac];
            bf16x8 AH = *(bf16x8*)&ah, AL = *(bf16x8*)&al;
            acc[0] = __builtin_amdgcn_mfma_f32_16x16x32_bf16(AH, BH0, acc[0], 0, 0, 0);
            acc[0] = __builtin_amdgcn_mfma_f32_16x16x32_bf16(AH, BL0, acc[0], 0, 0, 0);
            acc[0] = __builtin_amdgcn_mfma_f32_16x16x32_bf16(AL, BH0, acc[0], 0, 0, 0);
            acc[1] = __builtin_amdgcn_mfma_f32_16x16x32_bf16(AH, BH1, acc[1], 0, 0, 0);
            acc[1] = __builtin_amdgcn_mfma_f32_16x16x32_bf16(AH, BL1, acc[1], 0, 0, 0);
            acc[1] = __builtin_amdgcn_mfma_f32_16x16x32_bf16(AL, BH1, acc[1], 0, 0, 0);
        }

        if (L < 3) {
            // bias + leaky_relu -> xs
            const float* bias = (L == 0) ? (b_in + s*256) : (b_h + (s*2 + (L-1))*256);
            const float bb0 = bias[wv*32 + m0];
            const float bb1 = bias[wv*32 + 16 + m0];
            #pragma unroll
            for (int r = 0; r < 4; ++r) {
                int row = ac*4 + r;
                float v0 = acc[0][r] + bb0;
                float v1 = acc[1][r] + bb1;
                v0 = (v0 >= 0.f) ? v0 : 0.2f*v0;
                v1 = (v1 >= 0.f) ? v1 : 0.2f*v1;
                xs[row*260 + wv*32 + m0]      = v0;
                xs[row*260 + wv*32 + 16 + m0] = v1;
            }
            __syncthreads();

            // LN stats: wave wv reduces rows 2wv, 2wv+1
            #pragma unroll
            for (int i = 0; i < 2; ++i) {
                int row = wv*2 + i;
                float s1 = 0.f, s2 = 0.f;
                #pragma unroll
                for (int j = 0; j < 4; ++j) {
                    float v = xs[row*260 + l + 64*j];
                    s1 += v; s2 += v*v;
                }
                #pragma unroll
                for (int o = 32; o > 0; o >>= 1) {
                    s1 += __shfl_xor(s1, o, 64);
                    s2 += __shfl_xor(s2, o, 64);
                }
                if (l == 0) {
                    float m   = s1 * (1.f/256.f);
                    float var = s2 * (1.f/256.f) - m*m;
                    mrow[row] = m;
                    rrow[row] = rsqrtf(var + 1e-5f);
                }
            }
            __syncthreads();

            // normalize + split -> xh/xl (2048 k-pairs)
            #pragma unroll
            for (int i = 0; i < 4; ++i) {
                int idx = tid + i*512;
                int r = idx >> 7, kp = idx & 127;
                float mm = mrow[r], rr = rrow[r];
                float u = (xs[r*260 + 2*kp    ] - mm) * rr;
                float v = (xs[r*260 + 2*kp + 1] - mm) * rr;
                unsigned int uh = pk_bf16(u, v);
                xh[r*132 + kp] = uh;
                xl[r*132 + kp] = pk_bf16(u - bf_lo(uh), v - bf_hi(uh));
            }
            __syncthreads();
        } else {
            // L3: bias + direct store to out3 (cols 0..255)
            const float* bo = b_out + s*257;
            #pragma unroll
            for (int r = 0; r < 4; ++r) {
                int row = ac*4 + r;
                float* op = out3 + ((size_t)s*1024 + row0 + row)*257;
                op[wv*32 + m0]      = acc[0][r] + bo[wv*32 + m0];
                op[wv*32 + 16 + m0] = acc[1][r] + bo[wv*32 + 16 + m0];
            }
            // col 256: 32 threads per row over normalized L2 activations
            {
                int r   = tid >> 5;              // 0..15
                int c32 = tid & 31;
                float mm = mrow[r], rr = rrow[r];
                float p = 0.f;
                const float* w2 = Wout + (size_t)s*65792 + 256;
                #pragma unroll
                for (int j = 0; j < 8; ++j) {
                    int cc = c32*8 + j;
                    p = fmaf((xs[r*260 + cc] - mm) * rr, w2[(size_t)cc*257], p);
                }
                p += __shfl_xor(p, 1, 64);
                p += __shfl_xor(p, 2, 64);
                p += __shfl_xor(p, 4, 64);
                p += __shfl_xor(p, 8, 64);
                p += __shfl_xor(p, 16, 64);
                if (c32 == 0)
                    out3[((size_t)s*1024 + row0 + r)*257 + 256] = p + b_out[s*257 + 256];
            }
        }
    }
}

// ------------------------------------------------------------------
// K1: pack the quarter iDFT basis (unchanged)
// ------------------------------------------------------------------
__global__ __launch_bounds__(256) void tpack_init(unsigned short* __restrict__ tp)
{
    int g = blockIdx.x * 256 + threadIdx.x;      // 64*64 = 4096 threads exactly
    int tile = g >> 6, l = g & 63;
    int ks = tile >> 3;                          // 0..7
    int wv = tile & 7;
    int wg = wv >> 1, p = wv & 1;
    u16x8 v;
    #pragma unroll
    for (int j = 0; j < 8; ++j) {
        int k2 = ks*32 + ((l >> 4) << 3) + j;    // < 256
        int kap = (k2 >> 1) + 1;                 // 1..128
        int w  = wg*32 + 2*(l & 15) + p;         // < 128
        int m  = (kap * w) & 511;                // exact angle reduction
        float ang = (float)m * (PI_F / 256.f);
        float sn, cn; sincosf(ang, &sn, &cn);
        v[j] = f2bf((k2 & 1) ? sn : cn);
    }
    *(u16x8*)(tp + (size_t)g * 8) = v;
}

// ------------------------------------------------------------------
// K2: full-row fused scan + quarter-basis MFMA iDFT + Hann/OLA.
// ROUND 20: 4 sweeps of 32 frames -> LDS ~42.6 KB -> 3 blocks/CU
// (24 waves, +50% latency hiding).  Structure otherwise = round 18.
// ------------------------------------------------------------------
__global__ __launch_bounds__(512, 6) void synth_row(
    const float* __restrict__ out3,
    const float* __restrict__ phase0_u,
    const float* __restrict__ noise_u,
    const unsigned short* __restrict__ tpack,
    float* __restrict__ out)
{
    __shared__ __align__(16) unsigned int lds_u[8448];    // 33,792 B union
    __shared__ float a0s[32];
    __shared__ float a256s[32];
    __shared__ float pbuf[8][260];                        // 8,320 B
    __shared__ float xs128[32];
    __shared__ float xs384[32];

    unsigned int* abtP = lds_u;                  // [32][132] u32 (-> R_even)
    unsigned int* abtQ = lds_u + 32*132;         // [32][132] u32 (-> R_odd)
    float*        xbf  = (float*)lds_u;          // [16][516] f32

    const int tid = threadIdx.x;
    const int row = blockIdx.x;
    const int b   = row >> 9;
    const int e   = row & 511;

    const float inv = 0.04419417382415922f;      // 1/sqrt(512)

    // ---- producer init (tid <= 256): phase recurrence only ----
    float pr = 0.f, dith_ = 0.f, gdd = 0.f;
    if (tid <= 256) {
        float dpre = out3[((size_t)2*1024 + row)*257 + tid];
        dith_ = sigm(dpre);
        float gd = (float)tid * (1.f/512.f);
        gdd = gd - 0.5f*dith_;                   // pr += fma(dith, nz, gdd)
        pr  = phase0_u[(size_t)row*257 + tid] - 0.5f;
    }
    // thread 256: Nyquist-bin evaluation state
    float m2 = 0.f, res2_ = 0.f;
    if (tid == 256) {
        float i2 = out3[((size_t)0*1024 + row)*257 + 256];
        float r2 = out3[((size_t)1*1024 + row)*257 + 256];
        res2_ = 0.5f + 0.4995f * sigm(r2);
        m2    = inv * i2;
    }

    // ---- consumer init (all threads): bin kc, frames j0..j0+3 ----
    const int kc = tid & 255;
    const int j0 = (tid >> 8) * 4;               // 0 or 4
    float m_base, rp1, rp2, rp3, res8;
    float bsgn = -1.f;
    unsigned int* tgt = abtP;                    // kc==0 never writes tgt
    {
        float ini  = out3[((size_t)0*1024 + row)*257 + kc];
        float rpre = out3[((size_t)1*1024 + row)*257 + kc];
        float res  = 0.5f + 0.4995f * sigm(rpre);
        float cs   = (kc == 0 ? 1.f : 2.f) * inv;
        rp1 = res;
        rp2 = res * res;
        rp3 = rp2 * res;
        float res4 = rp2 * rp2;
        res8 = res4 * res4;
        m_base = cs * ini;
        if (j0 == 4) m_base *= res4;
        if (kc >= 129)     { tgt = abtQ + (255 - kc); bsgn = 1.f; }
        else if (kc >= 1)  { tgt = abtP + (kc - 1); }
    }

    const float* nrow = noise_u + ((size_t)b*128*512 + e)*257;
    const size_t nstride = (size_t)512*257;

    // OLA constants for col w = tid (threads < 256)
    float h1 = 0.f, h2 = 0.f;
    {
        float c0 = __builtin_amdgcn_cosf((float)tid * (1.f/512.f));
        h1 = 0.5f - 0.5f*c0;                     // hann[tid]
        h2 = 0.5f + 0.5f*c0;                     // hann[tid+256]
    }
    const float sgn = (tid & 1) ? -1.f : 1.f;    // (-1)^w
    float tail = 0.f;

    const int l  = tid & 63;
    const int wv = tid >> 6;                     // 0..7: one 16-src-col tile
    const int m0 = l & 15;
    const int ac = l >> 4;
    const int wsrc = (wv >> 1)*32 + 2*m0 + (wv & 1);   // source col 0..127
    const int c1 = wsrc;                         // x[w]
    const int c2 = wsrc + 256;                   // x[w+256]
    const int c3 = 256 - wsrc;                   // x[256-w]
    const int c4 = 512 - wsrc;                   // x[512-w] (invalid at w=0)
    const bool c4ok = (wsrc != 0);
    const int4* abtP4 = (const int4*)abtP;       // row stride 33 int4
    const int4* abtQ4 = (const int4*)abtQ;
    const int4* abtR4 = (wv & 1) ? abtQ4 : abtP4;   // parity-selected R
    const int4* Tp    = (const int4*)tpack;
    const unsigned int S   = 0x80008000u;
    const unsigned int B31 = 0x80000000u;

    for (int sweep = 0; sweep < 4; ++sweep) {
        const int F0 = sweep * 32;

        // ---- phase 1: producer/consumer scan, 4 groups of 8 frames ----
        for (int g = 0; g < 4; ++g) {
            if (tid <= 256) {
                float nzb[8];
                #pragma unroll
                for (int j = 0; j < 8; ++j) {
                    int t = F0 + g*8 + j;
                    nzb[j] = (t >= 1) ? __builtin_nontemporal_load(
                                            &nrow[(size_t)t*nstride + tid]) : 0.5f;
                }
                #pragma unroll
                for (int j = 0; j < 8; ++j) {
                    int t = F0 + g*8 + j;
                    if (t >= 1) pr += fmaf(dith_, nzb[j], gdd);
                    pbuf[j][tid] = pr;
                    if (tid == 256) {            // Nyquist: cos only
                        if (t >= 1) m2 *= res2_;
                        float fr = pr - floorf(pr);
                        a256s[g*8 + j] = m2 * __builtin_amdgcn_cosf(fr);
                    }
                }
            } else if (g == 0 && tid >= 480) {
                // zero abtQ kappa=128 column (clobbered by xbf each sweep)
                abtQ[(tid - 480)*132 + 127] = 0;
            }
            __syncthreads();

            // consumers: all 512 threads, 4 (bin,frame) items each
            {
                const int fb = g*8 + j0;
                float mv[4];
                mv[0] = m_base;
                mv[1] = m_base * rp1;
                mv[2] = m_base * rp2;
                mv[3] = m_base * rp3;
                #pragma unroll
                for (int q = 0; q < 4; ++q) {
                    float p  = pbuf[j0 + q][kc];
                    float fr = p - floorf(p);
                    float sn = __builtin_amdgcn_sinf(fr);
                    float cn = __builtin_amdgcn_cosf(fr);
                    float a  = mv[q] * cn;
                    if (kc == 0) {
                        a0s[fb + q] = a;
                    } else {
                        float bv = bsgn * mv[q] * sn;
                        tgt[(fb + q)*132] = pk_bf16(a, bv);
                    }
                }
                m_base *= res8;
            }
            __syncthreads();
        }

        // ---- phase 1.5: P/Q combine (in place): P<-P+Q, Q<-P-Q ----
        {
            #pragma unroll
            for (int i = 0; i < 8; ++i) {
                int idx = tid + i*512;           // 0..4095
                int f  = idx >> 7, ki = idx & 127;
                int o  = f*132 + ki;
                unsigned int up = abtP[o];
                unsigned int uq = abtQ[o];
                float aP = bf_lo(up), bP = bf_hi(up);
                float aQ = bf_lo(uq), bQ = bf_hi(uq);
                abtP[o] = pk_bf16(aP + aQ, bP + bQ);
                abtQ[o] = pk_bf16(aP - aQ, bP - bQ);
            }
        }
        __syncthreads();

        // ---- phase 2: MFMA  M=32, N=128 src cols x 4 mirror variants ----
        f32x4 acc1[2], acc2[2], acc3[2], acc4[2];
        #pragma unroll
        for (int mt = 0; mt < 2; ++mt) {
            acc1[mt] = (f32x4){0.f, 0.f, 0.f, 0.f};
            acc2[mt] = (f32x4){0.f, 0.f, 0.f, 0.f};
            acc3[mt] = (f32x4){0.f, 0.f, 0.f, 0.f};
            acc4[mt] = (f32x4){0.f, 0.f, 0.f, 0.f};
        }
        {
            const int r0g = m0*33 + ac;
            for (int ks = 0; ks < 8; ++ks) {
                int4 bi = Tp[(size_t)((ks*8 + wv) << 6) + l];
                bf16x8 B = *(bf16x8*)&bi;
                #pragma unroll
                for (int mt = 0; mt < 2; ++mt) {
                    int4 t = abtR4[r0g + mt*528 + ks*4];
                    acc1[mt] = __builtin_amdgcn_mfma_f32_16x16x32_bf16(*(bf16x8*)&t, B, acc1[mt], 0, 0, 0);
                    t.x ^= S;   t.z ^= S;                              // v2: flip odd kappa
                    acc2[mt] = __builtin_amdgcn_mfma_f32_16x16x32_bf16(*(bf16x8*)&t, B, acc2[mt], 0, 0, 0);
                    t.x ^= B31; t.y ^= B31; t.z ^= B31; t.w ^= B31;    // v3
                    acc3[mt] = __builtin_amdgcn_mfma_f32_16x16x32_bf16(*(bf16x8*)&t, B, acc3[mt], 0, 0, 0);
                    t.x ^= S;   t.z ^= S;                              // v4: b negated
                    acc4[mt] = __builtin_amdgcn_mfma_f32_16x16x32_bf16(*(bf16x8*)&t, B, acc4[mt], 0, 0, 0);
                }
            }
        }

        // ---- phase 2.5: specials x[128], x[384] from combined E coeffs ----
        if (tid < 256) {
            const int f8 = tid >> 3;             // frame 0..31
            const int i8 = tid & 7;              // kappa chunk
            float s128 = 0.f, s384 = 0.f;
            #pragma unroll
            for (int q = 0; q < 16; ++q) {
                int ki = i8*16 + q;              // kappa = ki+1
                unsigned int ue = abtP[f8*132 + ki];
                if ((q + 1) & 1) {               // kappa odd: sin terms
                    float sg = ((q + 1) & 2) ? -1.f : 1.f;
                    float bsum = bf_hi(ue);
                    s128 += sg * bsum;
                    s384 -= sg * bsum;
                } else {                         // kappa even: cos terms
                    float sg = ((q + 1) & 2) ? -1.f : 1.f;
                    float asum = bf_lo(ue);
                    s128 += sg * asum;
                    s384 += sg * asum;
                }
            }
            #pragma unroll
            for (int o = 1; o < 8; o <<= 1) {
                s128 += __shfl_xor(s128, o, 64);
                s384 += __shfl_xor(s384, o, 64);
            }
            if (i8 == 0) { xs128[f8] = s128; xs384[f8] = s384; }
        }
        __syncthreads();   // abt reads done; xbf may overwrite

        // ---- phase 3: two 16-frame halves: acc -> xbf -> Hann+OLA ----
        #pragma unroll
        for (int h = 0; h < 2; ++h) {
            #pragma unroll
            for (int r = 0; r < 4; ++r) {
                int f_loc = ac*4 + r;
                float* xr = &xbf[f_loc*516];
                xr[c1] = acc1[h][r];
                xr[c2] = acc2[h][r];
                xr[c3] = acc3[h][r];
                if (c4ok) xr[c4] = acc4[h][r];
            }
            if (tid < 16) {
                xbf[tid*516 + 128] = xs128[h*16 + tid];
                xbf[tid*516 + 384] = xs384[h*16 + tid];
            }
            __syncthreads();
            if (tid < 256) {
                float* orow = out + (size_t)row*32768 + (size_t)(F0 + h*16)*256 + tid;
                #pragma unroll
                for (int f = 0; f < 16; ++f) {
                    int hf = h*16 + f;
                    float s  = a0s[hf] + sgn * a256s[hf];
                    float x1 = xbf[f*516 + tid] + s;
                    float x2 = xbf[f*516 + tid + 256] + s;
                    float v  = fmaf(x1, h1, tail);
                    tail = x2 * h2;
                    __builtin_nontemporal_store(v, &orow[f*256]);
                }
            }
            __syncthreads();   // xbf reads done before next write / next abt
        }
    }
}

// ------------------------------------------------------------------

extern "C" void kernel_launch(void* const* d_in, const int* in_sizes, int n_in,
                              void* d_out, int out_size, void* d_ws, size_t ws_size,
                              hipStream_t stream)
{
    const float* latents  = (const float*)d_in[0];
    const float* phase0_u = (const float*)d_in[1];
    const float* noise_u  = (const float*)d_in[2];
    const float* Win      = (const float*)d_in[3];
    const float* b_in     = (const float*)d_in[4];
    const float* Wh       = (const float*)d_in[5];
    const float* b_h      = (const float*)d_in[6];
    const float* Wout     = (const float*)d_in[7];
    const float* b_out    = (const float*)d_in[8];

    unsigned char* ws = (unsigned char*)d_ws;
    float*          out3  = (float*)(ws + OUT3_OFF);
    unsigned short* tpack = (unsigned short*)(ws + TPACK_OFF);
    unsigned short* wp    = (unsigned short*)(ws + WPACK_OFF);
    float*          out   = (float*)d_out;

    wpack<<<336, 256, 0, stream>>>(Win, Wh, Wout, wp);
    dim3 gM(64, 3);
    mlp_mfma<<<gM, 512, 0, stream>>>(latents, b_in, b_h, b_out, Wout, wp, out3);
    tpack_init<<<16, 256, 0, stream>>>(tpack);
    synth_row<<<1024, 512, 0, stream>>>(out3, phase0_u, noise_u, tpack, out);
}

// Round 21
// 149.134 us; speedup vs baseline: 1.5563x; 1.5563x over previous
//
#include <hip/hip_runtime.h>
#include <hip/hip_bf16.h>

#define PI_F 3.14159265358979323846f

typedef short  bf16x8 __attribute__((ext_vector_type(8)));
typedef unsigned short u16x8 __attribute__((ext_vector_type(8)));
typedef float  f32x4  __attribute__((ext_vector_type(4)));

// ---- ws layout (bytes) ----
#define OUT3_OFF  0                       // [3][1024][257] f32 = 3,158,016 B
#define TPACK_OFF 3158016                 // [64 tiles][64][8] bf16 = 65,536 B
#define WPACK_OFF (3158016 + 65536)       // 1344 tile-pairs x 2 KB = 2,752,512 B

static __device__ __forceinline__ unsigned short f2bf(float x) {
    unsigned int u = __float_as_uint(x);
    unsigned int r = (u + 0x7fffu + ((u >> 16) & 1u)) >> 16;   // RNE
    return (unsigned short)r;
}

// pack two f32 -> one u32 of 2 bf16 (lo = a, hi = b) in ONE instruction
static __device__ __forceinline__ unsigned int pk_bf16(float a, float b) {
    unsigned int r;
    asm("v_cvt_pk_bf16_f32 %0, %1, %2" : "=v"(r) : "v"(a), "v"(b));
    return r;
}

static __device__ __forceinline__ float sigm(float x) {
    return 1.f / (1.f + expf(-x));
}

static __device__ __forceinline__ float bf_lo(unsigned int u) {
    return __uint_as_float(u << 16);
}
static __device__ __forceinline__ float bf_hi(unsigned int u) {
    return __uint_as_float(u & 0xffff0000u);
}

// ------------------------------------------------------------------
// wpack: pre-split all MLP weights into bf16 hi/lo B-fragment tiles.
// ------------------------------------------------------------------
__global__ __launch_bounds__(256) void wpack(
    const float* __restrict__ Win, const float* __restrict__ Wh,
    const float* __restrict__ Wout, unsigned short* __restrict__ wp)
{
    int g = blockIdx.x * 256 + threadIdx.x;     // 1344*64 = 86016 exactly
    int t = g >> 6, l = g & 63;
    int s = t / 448, lt = t % 448;
    int layer, base;
    if (lt < 64)       { layer = 0; base = 0;   }
    else if (lt < 192) { layer = 1; base = 64;  }
    else if (lt < 320) { layer = 2; base = 192; }
    else               { layer = 3; base = 320; }
    int local = lt - base, ks = local >> 4, nt = local & 15;

    u16x8 hv, lv;
    #pragma unroll
    for (int j = 0; j < 8; ++j) {
        int k = ks*32 + ((l >> 4) << 3) + j;
        int n = nt*16 + (l & 15);
        float w;
        if (layer == 0)      w = Win[(size_t)s*32768 + k*256 + n];
        else if (layer == 1) w = Wh[((size_t)s*2 + 0)*65536 + k*256 + n];
        else if (layer == 2) w = Wh[((size_t)s*2 + 1)*65536 + k*256 + n];
        else                 w = Wout[(size_t)s*65792 + k*257 + n];
        unsigned int ph = pk_bf16(w, 0.f);
        float fh = bf_lo(ph);
        hv[j] = (unsigned short)(ph & 0xffffu);
        lv[j] = (unsigned short)(pk_bf16(w - fh, 0.f) & 0xffffu);
    }
    *(u16x8*)(wp + (size_t)(t*2    )*512 + l*8) = hv;
    *(u16x8*)(wp + (size_t)(t*2 + 1)*512 + l*8) = lv;
}

// ------------------------------------------------------------------
// mlp_mfma: three LinearOutputStacks via split-bf16 MFMA.
// 16 rows/block, grid (64, 3) = 192 blocks (round-20 proven).
// ------------------------------------------------------------------
__global__ __launch_bounds__(512) void mlp_mfma(
    const float* __restrict__ latents,
    const float* __restrict__ b_in, const float* __restrict__ b_h,
    const float* __restrict__ b_out, const float* __restrict__ Wout,
    const unsigned short* __restrict__ wp,
    float* __restrict__ out3)
{
    __shared__ float xs[16*260];                 // 16,640 B fp32 staging
    __shared__ unsigned int xh[16*132];          // 8,448 B bf16-hi pairs
    __shared__ unsigned int xl[16*132];          // 8,448 B bf16-lo pairs
    __shared__ float mrow[16], rrow[16];

    const int tid  = threadIdx.x;
    const int s    = blockIdx.y;
    const int row0 = blockIdx.x * 16;
    const int l  = tid & 63;
    const int wv = tid >> 6;                     // 0..7: 32-col slice
    const int m0 = l & 15;
    const int ac = l >> 4;

    const int4* Wp4 = (const int4*)wp;
    const int4* xh4 = (const int4*)xh;           // row stride 33 int4
    const int4* xl4 = (const int4*)xl;

    // ---- load + split latents (K=128): 1024 k-pairs ----
    #pragma unroll
    for (int i = 0; i < 2; ++i) {
        int idx = tid + i*512;
        int r = idx >> 6, kp = idx & 63;
        const float* lp = latents + (size_t)(row0 + r)*128 + 2*kp;
        float x0 = lp[0], x1 = lp[1];
        unsigned int u = pk_bf16(x0, x1);
        xh[r*132 + kp] = u;
        xl[r*132 + kp] = pk_bf16(x0 - bf_lo(u), x1 - bf_hi(u));
    }
    __syncthreads();

    for (int L = 0; L < 4; ++L) {
        const int kt    = (L == 0) ? 4 : 8;
        const int tbase = s*448 + ((L == 0) ? 0 : (L == 1) ? 64 : (L == 2) ? 192 : 320);

        f32x4 acc[2];
        acc[0] = (f32x4){0.f, 0.f, 0.f, 0.f};
        acc[1] = (f32x4){0.f, 0.f, 0.f, 0.f};

        for (int ks = 0; ks < kt; ++ks) {
            const int t0 = tbase + ks*16 + wv*2;
            int4 bh0 = Wp4[(size_t)(t0*2    )*64 + l];
            int4 bl0 = Wp4[(size_t)(t0*2 + 1)*64 + l];
            int4 bh1 = Wp4[(size_t)(t0*2 + 2)*64 + l];
            int4 bl1 = Wp4[(size_t)(t0*2 + 3)*64 + l];
            bf16x8 BH0 = *(bf16x8*)&bh0, BL0 = *(bf16x8*)&bl0;
            bf16x8 BH1 = *(bf16x8*)&bh1, BL1 = *(bf16x8*)&bl1;
            int4 ah = xh4[m0*33 + ks*4 + ac];
            int4 al = xl4[m0*33 + ks*4 + ac];
            bf16x8 AH = *(bf16x8*)&ah, AL = *(bf16x8*)&al;
            acc[0] = __builtin_amdgcn_mfma_f32_16x16x32_bf16(AH, BH0, acc[0], 0, 0, 0);
            acc[0] = __builtin_amdgcn_mfma_f32_16x16x32_bf16(AH, BL0, acc[0], 0, 0, 0);
            acc[0] = __builtin_amdgcn_mfma_f32_16x16x32_bf16(AL, BH0, acc[0], 0, 0, 0);
            acc[1] = __builtin_amdgcn_mfma_f32_16x16x32_bf16(AH, BH1, acc[1], 0, 0, 0);
            acc[1] = __builtin_amdgcn_mfma_f32_16x16x32_bf16(AH, BL1, acc[1], 0, 0, 0);
            acc[1] = __builtin_amdgcn_mfma_f32_16x16x32_bf16(AL, BH1, acc[1], 0, 0, 0);
        }

        if (L < 3) {
            const float* bias = (L == 0) ? (b_in + s*256) : (b_h + (s*2 + (L-1))*256);
            const float bb0 = bias[wv*32 + m0];
            const float bb1 = bias[wv*32 + 16 + m0];
            #pragma unroll
            for (int r = 0; r < 4; ++r) {
                int row = ac*4 + r;
                float v0 = acc[0][r] + bb0;
                float v1 = acc[1][r] + bb1;
                v0 = (v0 >= 0.f) ? v0 : 0.2f*v0;
                v1 = (v1 >= 0.f) ? v1 : 0.2f*v1;
                xs[row*260 + wv*32 + m0]      = v0;
                xs[row*260 + wv*32 + 16 + m0] = v1;
            }
            __syncthreads();

            #pragma unroll
            for (int i = 0; i < 2; ++i) {
                int row = wv*2 + i;
                float s1 = 0.f, s2 = 0.f;
                #pragma unroll
                for (int j = 0; j < 4; ++j) {
                    float v = xs[row*260 + l + 64*j];
                    s1 += v; s2 += v*v;
                }
                #pragma unroll
                for (int o = 32; o > 0; o >>= 1) {
                    s1 += __shfl_xor(s1, o, 64);
                    s2 += __shfl_xor(s2, o, 64);
                }
                if (l == 0) {
                    float m   = s1 * (1.f/256.f);
                    float var = s2 * (1.f/256.f) - m*m;
                    mrow[row] = m;
                    rrow[row] = rsqrtf(var + 1e-5f);
                }
            }
            __syncthreads();

            #pragma unroll
            for (int i = 0; i < 4; ++i) {
                int idx = tid + i*512;
                int r = idx >> 7, kp = idx & 127;
                float mm = mrow[r], rr = rrow[r];
                float u = (xs[r*260 + 2*kp    ] - mm) * rr;
                float v = (xs[r*260 + 2*kp + 1] - mm) * rr;
                unsigned int uh = pk_bf16(u, v);
                xh[r*132 + kp] = uh;
                xl[r*132 + kp] = pk_bf16(u - bf_lo(uh), v - bf_hi(uh));
            }
            __syncthreads();
        } else {
            const float* bo = b_out + s*257;
            #pragma unroll
            for (int r = 0; r < 4; ++r) {
                int row = ac*4 + r;
                float* op = out3 + ((size_t)s*1024 + row0 + row)*257;
                op[wv*32 + m0]      = acc[0][r] + bo[wv*32 + m0];
                op[wv*32 + 16 + m0] = acc[1][r] + bo[wv*32 + 16 + m0];
            }
            {
                int r   = tid >> 5;              // 0..15
                int c32 = tid & 31;
                float mm = mrow[r], rr = rrow[r];
                float p = 0.f;
                const float* w2 = Wout + (size_t)s*65792 + 256;
                #pragma unroll
                for (int j = 0; j < 8; ++j) {
                    int cc = c32*8 + j;
                    p = fmaf((xs[r*260 + cc] - mm) * rr, w2[(size_t)cc*257], p);
                }
                p += __shfl_xor(p, 1, 64);
                p += __shfl_xor(p, 2, 64);
                p += __shfl_xor(p, 4, 64);
                p += __shfl_xor(p, 8, 64);
                p += __shfl_xor(p, 16, 64);
                if (c32 == 0)
                    out3[((size_t)s*1024 + row0 + r)*257 + 256] = p + b_out[s*257 + 256];
            }
        }
    }
}

// ------------------------------------------------------------------
// K1: pack the quarter iDFT basis (unchanged)
// ------------------------------------------------------------------
__global__ __launch_bounds__(256) void tpack_init(unsigned short* __restrict__ tp)
{
    int g = blockIdx.x * 256 + threadIdx.x;      // 64*64 = 4096 threads exactly
    int tile = g >> 6, l = g & 63;
    int ks = tile >> 3;                          // 0..7
    int wv = tile & 7;
    int wg = wv >> 1, p = wv & 1;
    u16x8 v;
    #pragma unroll
    for (int j = 0; j < 8; ++j) {
        int k2 = ks*32 + ((l >> 4) << 3) + j;    // < 256
        int kap = (k2 >> 1) + 1;                 // 1..128
        int w  = wg*32 + 2*(l & 15) + p;         // < 128
        int m  = (kap * w) & 511;                // exact angle reduction
        float ang = (float)m * (PI_F / 256.f);
        float sn, cn; sincosf(ang, &sn, &cn);
        v[j] = f2bf((k2 & 1) ? sn : cn);
    }
    *(u16x8*)(tp + (size_t)g * 8) = v;
}

// ------------------------------------------------------------------
// K2: full-row fused scan + quarter-basis MFMA iDFT + Hann/OLA.
// Base = round-19 (2 sweeps of 64, best verified).  NEW: the P/Q
// combine is FUSED into the scan consumer: lane pair (2m, 2m+1) owns
// mirror bins (kappa=m+1, 256-m); a shfl_xor(1) exchanges (a,b) and
// the pair writes final R_even/R_odd entries directly.  The separate
// combine pass, its barrier, and the abtQ-zeroing step are deleted.
// ------------------------------------------------------------------
__global__ __launch_bounds__(512, 4) void synth_row(
    const float* __restrict__ out3,
    const float* __restrict__ phase0_u,
    const float* __restrict__ noise_u,
    const unsigned short* __restrict__ tpack,
    float* __restrict__ out)
{
    __shared__ __align__(16) unsigned int lds_u[16896];   // 67,584 B union
    __shared__ float a0s[64];
    __shared__ float a256s[64];
    __shared__ float pbuf[8][260];                        // 8,320 B
    __shared__ float xs128[64];
    __shared__ float xs384[64];

    unsigned int* abtP = lds_u;                  // [64][132] u32 (R_even)
    unsigned int* abtQ = lds_u + 64*132;         // [64][132] u32 (R_odd)
    float*        xbf  = (float*)lds_u;          // [32][516] f32

    const int tid = threadIdx.x;
    const int row = blockIdx.x;
    const int b   = row >> 9;
    const int e   = row & 511;

    const float inv = 0.04419417382415922f;      // 1/sqrt(512)

    // ---- producer init (tid <= 256): phase recurrence only ----
    float pr = 0.f, dith_ = 0.f, gdd = 0.f;
    if (tid <= 256) {
        float dpre = out3[((size_t)2*1024 + row)*257 + tid];
        dith_ = sigm(dpre);
        float gd = (float)tid * (1.f/512.f);
        gdd = gd - 0.5f*dith_;                   // pr += fma(dith, nz, gdd)
        pr  = phase0_u[(size_t)row*257 + tid] - 0.5f;
    }
    // thread 256: Nyquist-bin evaluation state
    float m2 = 0.f, res2_ = 0.f;
    if (tid == 256) {
        float i2 = out3[((size_t)0*1024 + row)*257 + 256];
        float r2 = out3[((size_t)1*1024 + row)*257 + 256];
        res2_ = 0.5f + 0.4995f * sigm(r2);
        m2    = inv * i2;
    }

    // ---- consumer init: paired-bin assignment ----
    // lane pair (2m, 2m+1) -> bins (m+1 [P-side], 255-m [Q-side]);
    // pair m=127 -> (bin 128 [P, no partner], bin 0 [a0s]).
    const int i8b   = tid & 255;
    const int pairm = i8b >> 1;                  // 0..127
    const int side  = i8b & 1;                   // 0 = P, 1 = Q
    const int kc    = (pairm < 127) ? (side ? 255 - pairm : pairm + 1)
                                    : (side ? 0 : 128);
    const int j0 = (tid >> 8) * 4;               // 0 or 4
    float m_base, rp1, rp2, rp3, res8;
    float bsgn = (kc >= 129) ? 1.f : -1.f;
    {
        float ini  = out3[((size_t)0*1024 + row)*257 + kc];
        float rpre = out3[((size_t)1*1024 + row)*257 + kc];
        float res  = 0.5f + 0.4995f * sigm(rpre);
        float cs   = (kc == 0 ? 1.f : 2.f) * inv;
        rp1 = res;
        rp2 = res * res;
        rp3 = rp2 * res;
        float res4 = rp2 * rp2;
        res8 = res4 * res4;
        m_base = cs * ini;
        if (j0 == 4) m_base *= res4;
    }

    const float* nrow = noise_u + ((size_t)b*128*512 + e)*257;
    const size_t nstride = (size_t)512*257;

    // OLA constants for col w = tid (threads < 256)
    float h1 = 0.f, h2 = 0.f;
    {
        float c0 = __builtin_amdgcn_cosf((float)tid * (1.f/512.f));
        h1 = 0.5f - 0.5f*c0;                     // hann[tid]
        h2 = 0.5f + 0.5f*c0;                     // hann[tid+256]
    }
    const float sgn = (tid & 1) ? -1.f : 1.f;    // (-1)^w
    float tail = 0.f;

    const int l  = tid & 63;
    const int wv = tid >> 6;                     // 0..7: one 16-src-col tile
    const int m0 = l & 15;
    const int ac = l >> 4;
    const int wsrc = (wv >> 1)*32 + 2*m0 + (wv & 1);   // source col 0..127
    const int c1 = wsrc;                         // x[w]
    const int c2 = wsrc + 256;                   // x[w+256]
    const int c3 = 256 - wsrc;                   // x[256-w]
    const int c4 = 512 - wsrc;                   // x[512-w] (invalid at w=0)
    const bool c4ok = (wsrc != 0);
    const int4* abtP4 = (const int4*)abtP;       // row stride 33 int4
    const int4* abtQ4 = (const int4*)abtQ;
    const int4* abtR4 = (wv & 1) ? abtQ4 : abtP4;   // parity-selected R
    const int4* Tp    = (const int4*)tpack;
    const unsigned int S   = 0x80008000u;
    const unsigned int B31 = 0x80000000u;

    for (int sweep = 0; sweep < 2; ++sweep) {
        const int F0 = sweep * 64;

        // ---- phase 1: producer/consumer scan, 8 groups of 8 frames ----
        for (int g = 0; g < 8; ++g) {
            if (tid <= 256) {
                float nzb[8];
                #pragma unroll
                for (int j = 0; j < 8; ++j) {
                    int t = F0 + g*8 + j;
                    nzb[j] = (t >= 1) ? __builtin_nontemporal_load(
                                            &nrow[(size_t)t*nstride + tid]) : 0.5f;
                }
                #pragma unroll
                for (int j = 0; j < 8; ++j) {
                    int t = F0 + g*8 + j;
                    if (t >= 1) pr += fmaf(dith_, nzb[j], gdd);
                    pbuf[j][tid] = pr;
                    if (tid == 256) {            // Nyquist: cos only
                        if (t >= 1) m2 *= res2_;
                        float fr = pr - floorf(pr);
                        a256s[g*8 + j] = m2 * __builtin_amdgcn_cosf(fr);
                    }
                }
            }
            __syncthreads();

            // consumers: all 512 threads, 4 (bin,frame) items; pair-fused
            // combine writes final R tables directly.
            {
                const int fb = g*8 + j0;
                float mv[4];
                mv[0] = m_base;
                mv[1] = m_base * rp1;
                mv[2] = m_base * rp2;
                mv[3] = m_base * rp3;
                #pragma unroll
                for (int q = 0; q < 4; ++q) {
                    float p  = pbuf[j0 + q][kc];
                    float fr = p - floorf(p);
                    float sn = __builtin_amdgcn_sinf(fr);
                    float cn = __builtin_amdgcn_cosf(fr);
                    float a  = mv[q] * cn;
                    float bv = bsgn * mv[q] * sn;
                    float ao = __shfl_xor(a,  1, 64);
                    float bo = __shfl_xor(bv, 1, 64);
                    int off = (fb + q)*132 + pairm;
                    if (pairm < 127) {
                        if (side == 0) abtP[off] = pk_bf16(a + ao, bv + bo);
                        else           abtQ[off] = pk_bf16(ao - a, bo - bv);
                    } else if (side == 0) {      // kappa = 128, no Q partner
                        unsigned int u = pk_bf16(a, bv);
                        abtP[off] = u;
                        abtQ[off] = u;
                    } else {                     // bin 0
                        a0s[fb + q] = a;
                    }
                }
                m_base *= res8;
            }
            __syncthreads();
        }

        // ---- phase 2: MFMA  M=64, N=128 src cols x 4 mirror variants ----
        f32x4 acc1[4], acc2[4], acc3[4], acc4[4];
        #pragma unroll
        for (int mt = 0; mt < 4; ++mt) {
            acc1[mt] = (f32x4){0.f, 0.f, 0.f, 0.f};
            acc2[mt] = (f32x4){0.f, 0.f, 0.f, 0.f};
            acc3[mt] = (f32x4){0.f, 0.f, 0.f, 0.f};
            acc4[mt] = (f32x4){0.f, 0.f, 0.f, 0.f};
        }
        {
            const int r0g = m0*33 + ac;
            for (int ks = 0; ks < 8; ++ks) {
                int4 bi = Tp[(size_t)((ks*8 + wv) << 6) + l];
                bf16x8 B = *(bf16x8*)&bi;
                #pragma unroll
                for (int mt = 0; mt < 4; ++mt) {
                    int4 t = abtR4[r0g + mt*528 + ks*4];
                    acc1[mt] = __builtin_amdgcn_mfma_f32_16x16x32_bf16(*(bf16x8*)&t, B, acc1[mt], 0, 0, 0);
                    t.x ^= S;   t.z ^= S;                              // v2: flip odd kappa
                    acc2[mt] = __builtin_amdgcn_mfma_f32_16x16x32_bf16(*(bf16x8*)&t, B, acc2[mt], 0, 0, 0);
                    t.x ^= B31; t.y ^= B31; t.z ^= B31; t.w ^= B31;    // v3
                    acc3[mt] = __builtin_amdgcn_mfma_f32_16x16x32_bf16(*(bf16x8*)&t, B, acc3[mt], 0, 0, 0);
                    t.x ^= S;   t.z ^= S;                              // v4: b negated
                    acc4[mt] = __builtin_amdgcn_mfma_f32_16x16x32_bf16(*(bf16x8*)&t, B, acc4[mt], 0, 0, 0);
                }
            }
        }

        // ---- phase 2.5: specials x[128], x[384] from combined E coeffs ----
        {
            const int f8 = tid >> 3;             // frame 0..63
            const int i8 = tid & 7;              // kappa chunk
            float s128 = 0.f, s384 = 0.f;
            #pragma unroll
            for (int q = 0; q < 16; ++q) {
                int ki = i8*16 + q;              // kappa = ki+1
                unsigned int ue = abtP[f8*132 + ki];
                if ((q + 1) & 1) {               // kappa odd: sin terms
                    float sg = ((q + 1) & 2) ? -1.f : 1.f;
                    float bsum = bf_hi(ue);
                    s128 += sg * bsum;
                    s384 -= sg * bsum;
                } else {                         // kappa even: cos terms
                    float sg = ((q + 1) & 2) ? -1.f : 1.f;
                    float asum = bf_lo(ue);
                    s128 += sg * asum;
                    s384 += sg * asum;
                }
            }
            #pragma unroll
            for (int o = 1; o < 8; o <<= 1) {
                s128 += __shfl_xor(s128, o, 64);
                s384 += __shfl_xor(s384, o, 64);
            }
            if (i8 == 0) { xs128[f8] = s128; xs384[f8] = s384; }
        }
        __syncthreads();   // abt reads done; xbf may overwrite

        // ---- phase 3: two 32-frame halves: acc -> xbf -> Hann+OLA ----
        #pragma unroll
        for (int h = 0; h < 2; ++h) {
            #pragma unroll
            for (int mt2 = 0; mt2 < 2; ++mt2) {
                int mtg = 2*h + mt2;
                #pragma unroll
                for (int r = 0; r < 4; ++r) {
                    int f_loc = mt2*16 + ac*4 + r;
                    float* xr = &xbf[f_loc*516];
                    xr[c1] = acc1[mtg][r];
                    xr[c2] = acc2[mtg][r];
                    xr[c3] = acc3[mtg][r];
                    if (c4ok) xr[c4] = acc4[mtg][r];
                }
            }
            if (tid < 32) {
                xbf[tid*516 + 128] = xs128[h*32 + tid];
                xbf[tid*516 + 384] = xs384[h*32 + tid];
            }
            __syncthreads();
            if (tid < 256) {
                float* orow = out + (size_t)row*32768 + (size_t)(F0 + h*32)*256 + tid;
                #pragma unroll
                for (int f = 0; f < 32; ++f) {
                    int hf = h*32 + f;
                    float s  = a0s[hf] + sgn * a256s[hf];
                    float x1 = xbf[f*516 + tid] + s;
                    float x2 = xbf[f*516 + tid + 256] + s;
                    float v  = fmaf(x1, h1, tail);
                    tail = x2 * h2;
                    __builtin_nontemporal_store(v, &orow[f*256]);
                }
            }
            __syncthreads();   // xbf reads done before next write / next abt
        }
    }
}

// ------------------------------------------------------------------

extern "C" void kernel_launch(void* const* d_in, const int* in_sizes, int n_in,
                              void* d_out, int out_size, void* d_ws, size_t ws_size,
                              hipStream_t stream)
{
    const float* latents  = (const float*)d_in[0];
    const float* phase0_u = (const float*)d_in[1];
    const float* noise_u  = (const float*)d_in[2];
    const float* Win      = (const float*)d_in[3];
    const float* b_in     = (const float*)d_in[4];
    const float* Wh       = (const float*)d_in[5];
    const float* b_h      = (const float*)d_in[6];
    const float* Wout     = (const float*)d_in[7];
    const float* b_out    = (const float*)d_in[8];

    unsigned char* ws = (unsigned char*)d_ws;
    float*          out3  = (float*)(ws + OUT3_OFF);
    unsigned short* tpack = (unsigned short*)(ws + TPACK_OFF);
    unsigned short* wp    = (unsigned short*)(ws + WPACK_OFF);
    float*          out   = (float*)d_out;

    wpack<<<336, 256, 0, stream>>>(Win, Wh, Wout, wp);
    dim3 gM(64, 3);
    mlp_mfma<<<gM, 512, 0, stream>>>(latents, b_in, b_h, b_out, Wout, wp, out3);
    tpack_init<<<16, 256, 0, stream>>>(tpack);
    synth_row<<<1024, 512, 0, stream>>>(out3, phase0_u, noise_u, tpack, out);
}